// Round 6
// baseline (331.464 us; speedup 1.0000x reference)
//
#include <hip/hip_runtime.h>
#include <hip/hip_bf16.h>
#include <math.h>

#define LTOK 512
#define DDIM 512
#define NEXP 32
#define HDIM 512

typedef __attribute__((ext_vector_type(8))) short short8;
typedef __attribute__((ext_vector_type(4))) float floatx4;

// round-to-nearest-even fp32->bf16, packed pair: low16 = rne(a), high16 = rne(b)
__device__ __forceinline__ unsigned bpack(float a, float b) {
    unsigned ua = __float_as_uint(a), ub = __float_as_uint(b);
    ua += 0x7FFFu + ((ua >> 16) & 1u);
    ub += 0x7FFFu + ((ub >> 16) & 1u);
    return (ua >> 16) | (ub & 0xFFFF0000u);
}

// Tree grid barrier over 32 groups (blockIdx.y) x 32 blocks. Generation-based,
// counters never reset (barrier k expects count 32k+31). bar[] zeroed by a
// memsetAsync before each launch. Device-scope atomics + __threadfence for
// cross-XCD visibility (release stores before arrival, acquire after spin).
__device__ __forceinline__ void grid_sync(int* bar) {
    __syncthreads();
    if (threadIdx.x == 0) {
        int* gcnt = bar + (int)blockIdx.y * 16;   // 64B-strided per-group counters
        int* root = bar + 512;
        int* gen  = bar + 513;
        const int g = __hip_atomic_load(gen, __ATOMIC_RELAXED, __HIP_MEMORY_SCOPE_AGENT);
        __threadfence();   // release: xb/easgn/act stores visible before arrival
        const int tgt = 32 * (g + 1) - 1;
        const int v = __hip_atomic_fetch_add(gcnt, 1, __ATOMIC_ACQ_REL, __HIP_MEMORY_SCOPE_AGENT);
        if (v == tgt) {
            const int r = __hip_atomic_fetch_add(root, 1, __ATOMIC_ACQ_REL, __HIP_MEMORY_SCOPE_AGENT);
            if (r == tgt)
                __hip_atomic_store(gen, g + 1, __ATOMIC_RELEASE, __HIP_MEMORY_SCOPE_AGENT);
        }
        while (__hip_atomic_load(gen, __ATOMIC_RELAXED, __HIP_MEMORY_SCOPE_AGENT) <= g)
            __builtin_amdgcn_s_sleep(2);
        __threadfence();   // acquire: invalidate caches before reading others' data
    }
    __syncthreads();
}

// ws layout (bytes):
//   [0, 4K)        bar: 514 ints barrier state (memset to 0 each call)
//   [4K, 8K)       easgn: int[1024]   easgn[2t+k] = expert of token t's k-th pick
//   [8K, 12K)      wts:   float[1024] = routing weight * per_expert_scale
//   [12K, +512K)   xb:    512x512 bf16
//   [536576, +1M)  act:   1024x512 bf16
//
// Fused persistent kernel: grid (32 tiles, 32 experts) = 1024 blocks x 256 thr
// = exactly 4 blocks/CU under __launch_bounds__(256,4) -> all co-resident.
// Phase R (tile<16): router for token t = e*16+tile. All blocks preload their
// gates B (16 KB/wave) + linear B (8 KB/wave) into registers -- the 98 MB
// weight stream is in flight during the router phase. grid_sync; scan easgn;
// gates MFMA -> act; grid_sync; linear MFMA -> atomicAdd out.
__global__ __launch_bounds__(256, 4) void moe_fused(
    const float* __restrict__ x, const float* __restrict__ rs,
    const float* __restrict__ Wr, const float* __restrict__ pes,
    const float* __restrict__ G, const float* __restrict__ Wl,
    int* __restrict__ bar, int* __restrict__ easgn, float* __restrict__ wts,
    short* __restrict__ xb, short* __restrict__ act, float* __restrict__ out)
{
    const int tid  = threadIdx.x;
    const int e    = blockIdx.y;
    const int tile = blockIdx.x;
    const int wv   = tid >> 6;
    const int lane = tid & 63;
    const int n    = lane & 15;
    const int quad = lane >> 4;

    __shared__ float ri[DDIM];
    __shared__ float lgsp[8][32];
    __shared__ float lgs[NEXP];
    __shared__ float wsum[4];
    __shared__ int   toks[LTOK];
    __shared__ int   lcnt;
    __shared__ float red[4][2][4][64];   // 8 KB

    const int gg  = wv & 1;    // gate index (gates phase)
    const int kh  = wv >> 1;   // K half (gates phase)
    const int t16 = tile * 16; // h0 for gates, d0 for linear
    const float* Grow = G + ((size_t)((e * 2 + gg) * HDIM) + t16 + n) * DDIM + kh * 256;
    const float* Wcol = Wl + (size_t)e * HDIM * DDIM + t16 + n;

    // ---- Phase R: router (blocks with tile<16; one token each) ----
    if (tile < 16) {
        const int t = e * 16 + tile;
        const float2 xv = ((const float2*)(x + (size_t)t * DDIM))[tid];
        float ss = xv.x * xv.x + xv.y * xv.y;
#pragma unroll
        for (int o = 32; o > 0; o >>= 1) ss += __shfl_xor(ss, o);
        if (lane == 0) wsum[wv] = ss;
        __syncthreads();
        ss = (wsum[0] + wsum[1]) + (wsum[2] + wsum[3]);
        const float coef = rsqrtf(ss * (1.0f / 512.0f) + 1e-6f) * rsqrtf(512.0f);

        ((unsigned*)(xb + (size_t)t * DDIM))[tid] = bpack(xv.x, xv.y);
        float2 z; z.x = 0.f; z.y = 0.f;
        ((float2*)(out + (size_t)t * DDIM))[tid] = z;   // zero out row (linear atomicAdds later)
        const float2 rsv = ((const float2*)rs)[tid];
        ri[2 * tid]     = xv.x * coef * rsv.x;
        ri[2 * tid + 1] = xv.y * coef * rsv.y;
        __syncthreads();

        {   // logits: ee = tid&31 expert, seg = tid>>5 -> 64-d segment
            const int ee = tid & 31, seg = tid >> 5;
            const int d0 = seg * 64;
            float l0 = 0.f, l1 = 0.f, l2 = 0.f, l3 = 0.f;
#pragma unroll 4
            for (int d = d0; d < d0 + 64; d += 4) {
                l0 = fmaf(ri[d + 0], Wr[(d + 0) * NEXP + ee], l0);
                l1 = fmaf(ri[d + 1], Wr[(d + 1) * NEXP + ee], l1);
                l2 = fmaf(ri[d + 2], Wr[(d + 2) * NEXP + ee], l2);
                l3 = fmaf(ri[d + 3], Wr[(d + 3) * NEXP + ee], l3);
            }
            lgsp[seg][ee] = (l0 + l1) + (l2 + l3);
        }
        __syncthreads();
        if (tid < 32) {
            float lg = 0.f;
#pragma unroll
            for (int s = 0; s < 8; ++s) lg += lgsp[s][tid];
            lgs[tid] = lg;
        }
        __syncthreads();
        if (tid == 0) {
            int i0 = 0; float m0 = lgs[0];
            for (int i = 1; i < NEXP; ++i) if (lgs[i] > m0) { m0 = lgs[i]; i0 = i; }
            int i1 = -1; float m1 = -1e30f;
            for (int i = 0; i < NEXP; ++i) if (i != i0 && lgs[i] > m1) { m1 = lgs[i]; i1 = i; }
            // softmax denom cancels against renorm: weights depend only on top-2 logits
            const float e1 = expf(m1 - m0);
            const float inv = 1.0f / (1.0f + e1);
            easgn[2 * t]     = i0;
            easgn[2 * t + 1] = i1;
            wts[2 * t]     = inv * pes[i0];
            wts[2 * t + 1] = e1 * inv * pes[i1];
        }
    }

    // ---- Weight preload into registers (all blocks; overlaps router phase) ----
    short8 Bg[8];   // gates: this wave's gate-gg rows, K-half kh
#pragma unroll
    for (int ks = 0; ks < 8; ++ks) {
        const int ko = ks * 32 + quad * 8;
        const floatx4 b0 = *(const floatx4*)(Grow + ko);
        const floatx4 b1 = *(const floatx4*)(Grow + ko + 4);
        union { short8 s; unsigned u[4]; } B;
        B.u[0] = bpack(b0.x, b0.y);
        B.u[1] = bpack(b0.z, b0.w);
        B.u[2] = bpack(b1.x, b1.y);
        B.u[3] = bpack(b1.z, b1.w);
        Bg[ks] = B.s;
    }
    short8 Bl[4];   // linear: this wave's K-quarter column block
#pragma unroll
    for (int ks = 0; ks < 4; ++ks) {
        const int ko = wv * 128 + ks * 32 + quad * 8;
        float w[8];
#pragma unroll
        for (int j = 0; j < 8; ++j)
            w[j] = Wcol[(size_t)(ko + j) * DDIM];
        union { short8 s; unsigned u[4]; } B;
        B.u[0] = bpack(w[0], w[1]);
        B.u[1] = bpack(w[2], w[3]);
        B.u[2] = bpack(w[4], w[5]);
        B.u[3] = bpack(w[6], w[7]);
        Bl[ks] = B.s;
    }

    grid_sync(bar);   // router tables + xb visible; weight streams drained

    // ---- self-select scan (shared by gates & linear phases) ----
    if (tid == 0) lcnt = 0;
    __syncthreads();
    {
        const int4 eg = ((const int4*)easgn)[tid];   // slots 4*tid .. 4*tid+3
        if (eg.x == e) { int p = atomicAdd(&lcnt, 1); toks[p] = 4 * tid; }
        if (eg.y == e) { int p = atomicAdd(&lcnt, 1); toks[p] = 4 * tid + 1; }
        if (eg.z == e) { int p = atomicAdd(&lcnt, 1); toks[p] = 4 * tid + 2; }
        if (eg.w == e) { int p = atomicAdd(&lcnt, 1); toks[p] = 4 * tid + 3; }
    }
    __syncthreads();
    const int Ne = lcnt;

    // ---- gates phase ----
    if (Ne > 0) {
        const short* xbh = xb + kh * 256;
        for (int mb = 0; mb < Ne; mb += 32) {
            int arow[2];
#pragma unroll
            for (int i = 0; i < 2; ++i) {
                int s = mb + i * 16 + n;
                arow[i] = toks[s < Ne ? s : Ne - 1] >> 1;   // token index
            }
            floatx4 acc[2] = {};
#pragma unroll
            for (int ks = 0; ks < 8; ++ks) {
                const int ko = ks * 32 + quad * 8;
#pragma unroll
                for (int i = 0; i < 2; ++i) {
                    const short8 A = *(const short8*)(xbh + (size_t)arow[i] * DDIM + ko);
                    acc[i] = __builtin_amdgcn_mfma_f32_16x16x32_bf16(A, Bg[ks], acc[i], 0, 0, 0);
                }
            }
#pragma unroll
            for (int i = 0; i < 2; ++i)
#pragma unroll
                for (int r = 0; r < 4; ++r)
                    red[wv][i][r][lane] = acc[i][r];
            __syncthreads();
            // epilogue: wave handles m-tile (wv&1), regs {2u,2u+1}, u=wv>>1.
            // C/D: col = lane&15, row = quad*4 + r.
            {
                const int i = wv & 1;
                const int u = wv >> 1;
#pragma unroll
                for (int rr = 0; rr < 2; ++rr) {
                    const int r = u * 2 + rr;
                    const int s = mb + i * 16 + quad * 4 + r;
                    if (s < Ne) {
                        const int a = toks[s];   // slot id = act row
                        const float g0 = red[0][i][r][lane] + red[2][i][r][lane];
                        const float g1 = red[1][i][r][lane] + red[3][i][r][lane];
                        // gelu_tanh(g0) = g0 * sigmoid(2*u)
                        const float uu = 0.7978845608f * (g0 + 0.044715f * g0 * g0 * g0);
                        const float sg = 1.0f / (1.0f + __expf(-2.0f * uu));
                        const float v = g0 * sg * g1;
                        act[(size_t)a * HDIM + t16 + n] = (short)(bpack(v, 0.f) & 0xFFFFu);
                    }
                }
            }
            __syncthreads();
        }
    }

    grid_sync(bar);   // act visible across XCDs

    // ---- linear phase (reuses toks/Ne; d0 = t16) ----
    if (Ne > 0) {
        for (int mb = 0; mb < Ne; mb += 32) {
            int arow[2];
#pragma unroll
            for (int i = 0; i < 2; ++i) {
                int s = mb + i * 16 + n;
                arow[i] = toks[s < Ne ? s : Ne - 1];   // slot id = act row
            }
            floatx4 acc[2] = {};
#pragma unroll
            for (int ks = 0; ks < 4; ++ks) {
                const int ko = wv * 128 + ks * 32 + quad * 8;
#pragma unroll
                for (int i = 0; i < 2; ++i) {
                    const short8 A = *(const short8*)(act + (size_t)arow[i] * HDIM + ko);
                    acc[i] = __builtin_amdgcn_mfma_f32_16x16x32_bf16(A, Bl[ks], acc[i], 0, 0, 0);
                }
            }
#pragma unroll
            for (int i = 0; i < 2; ++i)
#pragma unroll
                for (int r = 0; r < 4; ++r)
                    red[wv][i][r][lane] = acc[i][r];
            __syncthreads();
            {
                const int i = wv & 1;
                const int u = wv >> 1;
#pragma unroll
                for (int rr = 0; rr < 2; ++rr) {
                    const int r = u * 2 + rr;
                    const int s = mb + i * 16 + quad * 4 + r;
                    if (s < Ne) {
                        const int slot = toks[s];
                        const float v = ((red[0][i][r][lane] + red[1][i][r][lane]) +
                                         (red[2][i][r][lane] + red[3][i][r][lane])) * wts[slot];
                        atomicAdd(&out[(size_t)(slot >> 1) * DDIM + t16 + n], v);
                    }
                }
            }
            __syncthreads();
        }
    }
}

extern "C" void kernel_launch(void* const* d_in, const int* in_sizes, int n_in,
                              void* d_out, int out_size, void* d_ws, size_t ws_size,
                              hipStream_t stream)
{
    const float* x   = (const float*)d_in[0];
    const float* rs  = (const float*)d_in[1];
    const float* Wr  = (const float*)d_in[2];
    const float* G   = (const float*)d_in[3];
    const float* Wl  = (const float*)d_in[4];
    const float* pes = (const float*)d_in[5];
    float* out = (float*)d_out;

    char* ws = (char*)d_ws;
    int*   bar   = (int*)(ws);
    int*   easgn = (int*)(ws + 4096);
    float* wts   = (float*)(ws + 8192);
    short* xb    = (short*)(ws + 12288);
    short* act   = (short*)(ws + 536576);

    hipMemsetAsync(bar, 0, 4096, stream);
    moe_fused<<<dim3(32, 32), dim3(256), 0, stream>>>(
        x, rs, Wr, pes, G, Wl, bar, easgn, wts, xb, act, out);
}

// Round 7
// 168.075 us; speedup vs baseline: 1.9721x; 1.9721x over previous
//
#include <hip/hip_runtime.h>
#include <hip/hip_bf16.h>
#include <math.h>

#define LTOK 512
#define DDIM 512
#define NEXP 32
#define HDIM 512

typedef __attribute__((ext_vector_type(8))) short short8;
typedef __attribute__((ext_vector_type(4))) float floatx4;

// round-to-nearest-even fp32->bf16, packed pair: low16 = rne(a), high16 = rne(b)
__device__ __forceinline__ unsigned bpack(float a, float b) {
    unsigned ua = __float_as_uint(a), ub = __float_as_uint(b);
    ua += 0x7FFFu + ((ua >> 16) & 1u);
    ub += 0x7FFFu + ((ub >> 16) & 1u);
    return (ua >> 16) | (ub & 0xFFFF0000u);
}

// ws layout (bytes):
//   [0, 4K)        easgn: int[1024]   easgn[2t+k] = expert of token t's k-th pick
//   [4K, 8K)       wts:   float[1024] = routing weight * per_expert_scale
//   [8K, +512K)    xb:    512x512 bf16 (x rounded to bf16)
// total ~520 KB; no memsets (dense tables; out zeroed by router)

__global__ __launch_bounds__(64) void router_kernel(
    const float* __restrict__ x, const float* __restrict__ rs,
    const float* __restrict__ Wr, const float* __restrict__ pes,
    int* __restrict__ easgn, float* __restrict__ wts,
    short* __restrict__ xb, float* __restrict__ out)
{
    const int t = blockIdx.x;
    const int lane = threadIdx.x;

    float xv[8];
    float ss = 0.f;
#pragma unroll
    for (int j = 0; j < 8; ++j) {
        xv[j] = x[t * DDIM + j * 64 + lane];
        ss += xv[j] * xv[j];
    }
    // emit bf16 copy of x for the expert GEMMs; zero this token's out row
#pragma unroll
    for (int j = 0; j < 8; ++j) {
        xb[t * DDIM + j * 64 + lane] = (short)(bpack(xv[j], 0.f) & 0xFFFFu);
        out[t * DDIM + j * 64 + lane] = 0.f;
    }

#pragma unroll
    for (int o = 32; o > 0; o >>= 1) ss += __shfl_xor(ss, o);
    const float var = ss * (1.0f / 512.0f);
    const float coef = rsqrtf(var + 1e-6f) * rsqrtf(512.0f);

    __shared__ float ri[DDIM];
#pragma unroll
    for (int j = 0; j < 8; ++j) {
        const int d = j * 64 + lane;
        ri[d] = xv[j] * coef * rs[d];
    }
    __syncthreads();

    // logits: lane&31 -> expert, lane>>5 -> half of D; 4 partial accs break the chain
    const int e = lane & 31;
    const int half = lane >> 5;
    const int dbeg = half * 256;
    float l0 = 0.f, l1 = 0.f, l2 = 0.f, l3 = 0.f;
#pragma unroll 4
    for (int d = dbeg; d < dbeg + 256; d += 4) {
        l0 = fmaf(ri[d + 0], Wr[(d + 0) * NEXP + e], l0);
        l1 = fmaf(ri[d + 1], Wr[(d + 1) * NEXP + e], l1);
        l2 = fmaf(ri[d + 2], Wr[(d + 2) * NEXP + e], l2);
        l3 = fmaf(ri[d + 3], Wr[(d + 3) * NEXP + e], l3);
    }
    float lg = (l0 + l1) + (l2 + l3);
    lg += __shfl_xor(lg, 32);

    __shared__ float lgs[NEXP];
    if (lane < 32) lgs[lane] = lg;
    __syncthreads();

    if (lane == 0) {
        int i0 = 0; float m0 = lgs[0];
        for (int i = 1; i < NEXP; ++i) if (lgs[i] > m0) { m0 = lgs[i]; i0 = i; }
        int i1 = -1; float m1 = -1e30f;
        for (int i = 0; i < NEXP; ++i) if (i != i0 && lgs[i] > m1) { m1 = lgs[i]; i1 = i; }
        // softmax denom cancels against renorm: weights depend only on top-2 logits
        const float e1 = expf(m1 - m0);
        const float inv = 1.0f / (1.0f + e1);
        easgn[2 * t]     = i0;
        easgn[2 * t + 1] = i1;
        wts[2 * t]     = inv * pes[i0];
        wts[2 * t + 1] = e1 * inv * pes[i1];
    }
}

// Fused expert kernel via K-chunk decomposition: block = (32-h chunk, expert).
// gates: act_win[slots, 32h] = glu(x @ G[e,:,h-chunk,:]^T) * wts  (in LDS)
// linear partial: out += act_win @ Wl[e][h-chunk, :]   (Hc=32 = one MFMA K-step)
// No cross-block dependency -> no grid sync, no act round-trip; G and Wl streams
// overlap. 4 waves: wv = (khalf<<1)|gate for the gates GEMM; each wave owns
// 128 d-columns (8 n-tiles) of the linear GEMM.
// launch_bounds(256,2): VGPR cap 256 -> deep load pipelining (R6's 60-VGPR choke
// was the regression cause); 2 blocks/CU.
__global__ __launch_bounds__(256, 2) void expert_kernel(
    const short* __restrict__ xb, const float* __restrict__ G,
    const float* __restrict__ Wl, const int* __restrict__ easgn,
    const float* __restrict__ wts, float* __restrict__ out)
{
    const int e  = blockIdx.y;
    const int h0 = blockIdx.x * 32;
    const int tid = threadIdx.x;
    const int wv   = tid >> 6;
    const int g    = wv & 1;    // gate index (gates phase)
    const int kh   = wv >> 1;   // K half (gates phase)
    const int lane = tid & 63;
    const int n    = lane & 15;
    const int quad = lane >> 4;

    __shared__ int   toks[LTOK];
    __shared__ float wsl[LTOK];
    __shared__ int   lcnt;
    __shared__ float red[4][2][2][4][64];          // [wave][m][nt][reg][lane] 16 KB
    __shared__ __align__(16) short act_win[32][40]; // 32 slots x 32 h bf16, pad 40

    // ---- gates B preload: 2 n-tiles x 8 ks (this wave's gate g, K-half kh) ----
    short8 Bg[2][8];
#pragma unroll
    for (int nt = 0; nt < 2; ++nt) {
        const float* Grow = G + ((size_t)((e * 2 + g) * HDIM) + h0 + nt * 16 + n) * DDIM + kh * 256;
#pragma unroll
        for (int ks = 0; ks < 8; ++ks) {
            const int ko = ks * 32 + quad * 8;
            const floatx4 b0 = *(const floatx4*)(Grow + ko);
            const floatx4 b1 = *(const floatx4*)(Grow + ko + 4);
            union { short8 s; unsigned u[4]; } B;
            B.u[0] = bpack(b0.x, b0.y);
            B.u[1] = bpack(b0.z, b0.w);
            B.u[2] = bpack(b1.x, b1.y);
            B.u[3] = bpack(b1.z, b1.w);
            Bg[nt][ks] = B.s;
        }
    }
    // ---- linear B preload: 8 n-tiles, K=32 (rows h0+quad*8+j, cols wv*128+nt2*16+n) ----
    short8 Bl[8];
#pragma unroll
    for (int nt2 = 0; nt2 < 8; ++nt2) {
        const float* Wcol = Wl + ((size_t)e * HDIM + h0 + quad * 8) * DDIM + wv * 128 + nt2 * 16 + n;
        float w[8];
#pragma unroll
        for (int j = 0; j < 8; ++j)
            w[j] = Wcol[(size_t)j * DDIM];
        union { short8 s; unsigned u[4]; } B;
        B.u[0] = bpack(w[0], w[1]);
        B.u[1] = bpack(w[2], w[3]);
        B.u[2] = bpack(w[4], w[5]);
        B.u[3] = bpack(w[6], w[7]);
        Bl[nt2] = B.s;
    }

    // ---- self-select scan (also caches routing scale) ----
    if (tid == 0) lcnt = 0;
    __syncthreads();
    {
        const int4 eg = ((const int4*)easgn)[tid];   // slots 4*tid .. 4*tid+3
        if (eg.x == e) { int p = atomicAdd(&lcnt, 1); toks[p] = 4 * tid;     wsl[p] = wts[4 * tid]; }
        if (eg.y == e) { int p = atomicAdd(&lcnt, 1); toks[p] = 4 * tid + 1; wsl[p] = wts[4 * tid + 1]; }
        if (eg.z == e) { int p = atomicAdd(&lcnt, 1); toks[p] = 4 * tid + 2; wsl[p] = wts[4 * tid + 2]; }
        if (eg.w == e) { int p = atomicAdd(&lcnt, 1); toks[p] = 4 * tid + 3; wsl[p] = wts[4 * tid + 3]; }
    }
    __syncthreads();
    const int Ne = lcnt;
    if (Ne == 0) return;

    const short* xbh = xb + kh * 256;

    for (int mb = 0; mb < Ne; mb += 32) {
        int arow[2];
#pragma unroll
        for (int i = 0; i < 2; ++i) {
            int s = mb + i * 16 + n;
            arow[i] = toks[s < Ne ? s : Ne - 1] >> 1;   // token index
        }

        // ---- gates GEMM: acc[m][nt], K-half kh, gate g ----
        floatx4 acc[2][2] = {};
#pragma unroll
        for (int ks = 0; ks < 8; ++ks) {
            const int ko = ks * 32 + quad * 8;
#pragma unroll
            for (int i = 0; i < 2; ++i) {
                const short8 A = *(const short8*)(xbh + (size_t)arow[i] * DDIM + ko);
#pragma unroll
                for (int nt = 0; nt < 2; ++nt)
                    acc[i][nt] = __builtin_amdgcn_mfma_f32_16x16x32_bf16(A, Bg[nt][ks], acc[i][nt], 0, 0, 0);
            }
        }
#pragma unroll
        for (int i = 0; i < 2; ++i)
#pragma unroll
            for (int nt = 0; nt < 2; ++nt)
#pragma unroll
                for (int r = 0; r < 4; ++r)
                    red[wv][i][nt][r][lane] = acc[i][nt][r];
        __syncthreads();

        // ---- glu epilogue -> act_win (wave handles pair m=wv&1, nt=wv>>1) ----
        // C/D: col = lane&15 (h), row = quad*4 + r (slot)
        {
            const int m  = wv & 1;
            const int nt = wv >> 1;
#pragma unroll
            for (int r = 0; r < 4; ++r) {
                const int s = mb + m * 16 + quad * 4 + r;
                if (s < Ne) {
                    const float g0 = red[0][m][nt][r][lane] + red[2][m][nt][r][lane];
                    const float g1 = red[1][m][nt][r][lane] + red[3][m][nt][r][lane];
                    // gelu_tanh(g0) = g0 * sigmoid(2*u)
                    const float uu = 0.7978845608f * (g0 + 0.044715f * g0 * g0 * g0);
                    const float sg = 1.0f / (1.0f + __expf(-2.0f * uu));
                    const float v = g0 * sg * g1 * wsl[s];   // routing scale folded in
                    act_win[m * 16 + quad * 4 + r][nt * 16 + n] = (short)(bpack(v, 0.f) & 0xFFFFu);
                }
            }
        }
        __syncthreads();

        // ---- linear partial: out[:, wv*128 + nt2*16 + n] += act_win @ Bl ----
        // A: row = lane&15 (slot), k = quad*8+j (h-local, K=32 exactly)
#pragma unroll
        for (int i = 0; i < 2; ++i) {
            const short8 Aw = *(const short8*)&act_win[i * 16 + n][quad * 8];
#pragma unroll
            for (int nt2 = 0; nt2 < 8; ++nt2) {
                floatx4 y = {};
                y = __builtin_amdgcn_mfma_f32_16x16x32_bf16(Aw, Bl[nt2], y, 0, 0, 0);
#pragma unroll
                for (int r = 0; r < 4; ++r) {
                    const int s = mb + i * 16 + quad * 4 + r;
                    if (s < Ne)
                        atomicAdd(&out[(size_t)(toks[s] >> 1) * DDIM + wv * 128 + nt2 * 16 + n], y[r]);
                }
            }
        }
        __syncthreads();   // protect red/act_win before next window
    }
}

extern "C" void kernel_launch(void* const* d_in, const int* in_sizes, int n_in,
                              void* d_out, int out_size, void* d_ws, size_t ws_size,
                              hipStream_t stream)
{
    const float* x   = (const float*)d_in[0];
    const float* rs  = (const float*)d_in[1];
    const float* Wr  = (const float*)d_in[2];
    const float* G   = (const float*)d_in[3];
    const float* Wl  = (const float*)d_in[4];
    const float* pes = (const float*)d_in[5];
    float* out = (float*)d_out;

    char* ws = (char*)d_ws;
    int*   easgn = (int*)(ws);
    float* wts   = (float*)(ws + 4096);
    short* xb    = (short*)(ws + 8192);

    router_kernel<<<dim3(LTOK), dim3(64), 0, stream>>>(x, rs, Wr, pes, easgn, wts, xb, out);
    expert_kernel<<<dim3(16, NEXP), dim3(256), 0, stream>>>(xb, G, Wl, easgn, wts, out);
}

// Round 8
// 157.694 us; speedup vs baseline: 2.1019x; 1.0658x over previous
//
#include <hip/hip_runtime.h>
#include <hip/hip_bf16.h>
#include <math.h>

#define LTOK 512
#define DDIM 512
#define NEXP 32
#define HDIM 512

typedef __attribute__((ext_vector_type(8))) short short8;
typedef __attribute__((ext_vector_type(4))) float floatx4;

// round-to-nearest-even fp32->bf16, packed pair: low16 = rne(a), high16 = rne(b)
__device__ __forceinline__ unsigned bpack(float a, float b) {
    unsigned ua = __float_as_uint(a), ub = __float_as_uint(b);
    ua += 0x7FFFu + ((ua >> 16) & 1u);
    ub += 0x7FFFu + ((ub >> 16) & 1u);
    return (ua >> 16) | (ub & 0xFFFF0000u);
}

// Async global->LDS DMA (zero VGPR cost). LDS dst = wave-uniform base + lane*size.
__device__ __forceinline__ void stage16(const float* g, void* l) {
    __builtin_amdgcn_global_load_lds(
        (const __attribute__((address_space(1))) void*)g,
        (__attribute__((address_space(3))) void*)l, 16, 0, 0);
}
__device__ __forceinline__ void stage4(const float* g, void* l) {
    __builtin_amdgcn_global_load_lds(
        (const __attribute__((address_space(1))) void*)g,
        (__attribute__((address_space(3))) void*)l, 4, 0, 0);
}

// ws layout (bytes):
//   [0, 4K)        easgn: int[1024]   easgn[2t+k] = expert of token t's k-th pick
//   [4K, 8K)       wts:   float[1024] = routing weight * per_expert_scale
//   [8K, +512K)    xb:    512x512 bf16 (x rounded to bf16)
//   [532480, +1M)  act:   1024x512 bf16 (slot-indexed activated gate output)

__global__ __launch_bounds__(64) void router_kernel(
    const float* __restrict__ x, const float* __restrict__ rs,
    const float* __restrict__ Wr, const float* __restrict__ pes,
    int* __restrict__ easgn, float* __restrict__ wts,
    short* __restrict__ xb, float* __restrict__ out)
{
    const int t = blockIdx.x;
    const int lane = threadIdx.x;

    float xv[8];
    float ss = 0.f;
#pragma unroll
    for (int j = 0; j < 8; ++j) {
        xv[j] = x[t * DDIM + j * 64 + lane];
        ss += xv[j] * xv[j];
    }
    // emit bf16 copy of x for the expert GEMMs; zero this token's out row
#pragma unroll
    for (int j = 0; j < 8; ++j) {
        xb[t * DDIM + j * 64 + lane] = (short)(bpack(xv[j], 0.f) & 0xFFFFu);
        out[t * DDIM + j * 64 + lane] = 0.f;
    }

#pragma unroll
    for (int o = 32; o > 0; o >>= 1) ss += __shfl_xor(ss, o);
    const float var = ss * (1.0f / 512.0f);
    const float coef = rsqrtf(var + 1e-6f) * rsqrtf(512.0f);

    __shared__ float ri[DDIM];
#pragma unroll
    for (int j = 0; j < 8; ++j) {
        const int d = j * 64 + lane;
        ri[d] = xv[j] * coef * rs[d];
    }
    __syncthreads();

    // logits: lane&31 -> expert, lane>>5 -> half of D; 4 partial accs break the chain
    const int e = lane & 31;
    const int half = lane >> 5;
    const int dbeg = half * 256;
    float l0 = 0.f, l1 = 0.f, l2 = 0.f, l3 = 0.f;
#pragma unroll 4
    for (int d = dbeg; d < dbeg + 256; d += 4) {
        l0 = fmaf(ri[d + 0], Wr[(d + 0) * NEXP + e], l0);
        l1 = fmaf(ri[d + 1], Wr[(d + 1) * NEXP + e], l1);
        l2 = fmaf(ri[d + 2], Wr[(d + 2) * NEXP + e], l2);
        l3 = fmaf(ri[d + 3], Wr[(d + 3) * NEXP + e], l3);
    }
    float lg = (l0 + l1) + (l2 + l3);
    lg += __shfl_xor(lg, 32);

    __shared__ float lgs[NEXP];
    if (lane < 32) lgs[lane] = lg;
    __syncthreads();

    if (lane == 0) {
        int i0 = 0; float m0 = lgs[0];
        for (int i = 1; i < NEXP; ++i) if (lgs[i] > m0) { m0 = lgs[i]; i0 = i; }
        int i1 = -1; float m1 = -1e30f;
        for (int i = 0; i < NEXP; ++i) if (i != i0 && lgs[i] > m1) { m1 = lgs[i]; i1 = i; }
        // softmax denom cancels against renorm: weights depend only on top-2 logits
        const float e1 = expf(m1 - m0);
        const float inv = 1.0f / (1.0f + e1);
        easgn[2 * t]     = i0;
        easgn[2 * t + 1] = i1;
        wts[2 * t]     = inv * pes[i0];
        wts[2 * t + 1] = e1 * inv * pes[i1];
    }
}

// grid (32, 32): blockIdx.x = 16-wide h tile, blockIdx.y = expert.
// 4 waves: wv = (khalf<<1)|gate. Wave's B chunk (16 h x 256 k fp32 = 16 KB) is
// staged to LDS via async global_load_lds in FRAGMENT ORDER (per-lane gather:
// instr (ks,half) -> lane l fetches 16B at row l&15, col ks*32+(l>>4)*8+half*4;
// lands at lane*16) so pack reads are contiguous & conflict-free. Zero VGPR
// staging cost -> 16 KB in flight per wave, 128 KB/CU.
// LDS aliasing: stage (64 KB) is dead after pack; red/toks overlay it (barrier
// after pack before overwrite). 64 KB block LDS -> 2 blocks/CU.
__global__ __launch_bounds__(256, 2) void gates_kernel(
    const short* __restrict__ xb, const float* __restrict__ G,
    const int* __restrict__ easgn, short* __restrict__ act)
{
    const int e  = blockIdx.y;
    const int h0 = blockIdx.x * 16;
    const int tid = threadIdx.x;
    const int wv   = tid >> 6;
    const int g    = wv & 1;    // gate index
    const int kh   = wv >> 1;   // K half
    const int lane = tid & 63;
    const int n    = lane & 15;
    const int quad = lane >> 4;

    __shared__ __align__(16) char smem[65536];
    // stage: [wv][16 KB] ; aliased after pack by:
    float (*red)[2][4][64] = (float(*)[2][4][64])smem;   // [4][2][4][64] = 8 KB
    int* toks = (int*)(smem + 8192);                     // 2 KB
    int* lcnt = (int*)(smem + 8192 + 2048);

    // easgn load issued FIRST so the scan waits at vmcnt(16), not vmcnt(0)
    const int4 eg = ((const int4*)easgn)[tid];   // slots 4*tid .. 4*tid+3

    // ---- async stage: 16 instrs x 1 KB per wave ----
    const float* Gl = G + ((size_t)((e * 2 + g) * HDIM) + h0 + n) * DDIM + kh * 256 + quad * 8;
    char* const swv = smem + wv * 16384;
#pragma unroll
    for (int ks = 0; ks < 8; ++ks) {
#pragma unroll
        for (int half = 0; half < 2; ++half)
            stage16(Gl + ks * 32 + half * 4, swv + (ks * 2 + half) * 1024);
    }

    // ---- pack to register fragments (wave-local; wait own DMA) ----
    __builtin_amdgcn_s_waitcnt(0x0f70);   // vmcnt(0)
    short8 Bg[8];
#pragma unroll
    for (int ks = 0; ks < 8; ++ks) {
        const floatx4 u0 = *(const floatx4*)(swv + ks * 2048 + lane * 16);
        const floatx4 u1 = *(const floatx4*)(swv + ks * 2048 + 1024 + lane * 16);
        union { short8 s; unsigned u[4]; } B;
        B.u[0] = bpack(u0.x, u0.y);
        B.u[1] = bpack(u0.z, u0.w);
        B.u[2] = bpack(u1.x, u1.y);
        B.u[3] = bpack(u1.z, u1.w);
        Bg[ks] = B.s;
    }
    __syncthreads();   // all packs done before toks/red overlay the stage

    // ---- self-select scan ----
    if (tid == 0) *lcnt = 0;
    __syncthreads();
    if (eg.x == e) { int p = atomicAdd(lcnt, 1); toks[p] = 4 * tid; }
    if (eg.y == e) { int p = atomicAdd(lcnt, 1); toks[p] = 4 * tid + 1; }
    if (eg.z == e) { int p = atomicAdd(lcnt, 1); toks[p] = 4 * tid + 2; }
    if (eg.w == e) { int p = atomicAdd(lcnt, 1); toks[p] = 4 * tid + 3; }
    __syncthreads();
    const int Ne = *lcnt;
    if (Ne == 0) return;

    const short* xbh = xb + kh * 256;

    for (int mb = 0; mb < Ne; mb += 32) {
        int arow[2];
#pragma unroll
        for (int i = 0; i < 2; ++i) {
            int s = mb + i * 16 + n;
            arow[i] = toks[s < Ne ? s : Ne - 1] >> 1;   // token index
        }
        floatx4 acc[2] = {};
#pragma unroll
        for (int ks = 0; ks < 8; ++ks) {
            const int ko = ks * 32 + quad * 8;
#pragma unroll
            for (int i = 0; i < 2; ++i) {
                const short8 A = *(const short8*)(xbh + (size_t)arow[i] * DDIM + ko);
                acc[i] = __builtin_amdgcn_mfma_f32_16x16x32_bf16(A, Bg[ks], acc[i], 0, 0, 0);
            }
        }
#pragma unroll
        for (int i = 0; i < 2; ++i)
#pragma unroll
            for (int r = 0; r < 4; ++r)
                red[wv][i][r][lane] = acc[i][r];
        __syncthreads();

        // epilogue: wave handles m-tile (wv&1), regs {2u,2u+1}, u=wv>>1.
        // C/D: col = lane&15, row = quad*4 + r.
        {
            const int i = wv & 1;
            const int u = wv >> 1;
#pragma unroll
            for (int rr = 0; rr < 2; ++rr) {
                const int r = u * 2 + rr;
                const int s = mb + i * 16 + quad * 4 + r;
                if (s < Ne) {
                    const int a = toks[s];   // slot id = act row
                    const float g0 = red[0][i][r][lane] + red[2][i][r][lane];
                    const float g1 = red[1][i][r][lane] + red[3][i][r][lane];
                    // gelu_tanh(g0) = g0 * sigmoid(2*u)
                    const float uu = 0.7978845608f * (g0 + 0.044715f * g0 * g0 * g0);
                    const float sg = 1.0f / (1.0f + __expf(-2.0f * uu));
                    const float v = g0 * sg * g1;
                    act[(size_t)a * HDIM + h0 + n] = (short)(bpack(v, 0.f) & 0xFFFFu);
                }
            }
        }
        __syncthreads();
    }
}

// grid (32, 32): blockIdx.x = 16-wide d tile, blockIdx.y = expert.
// 4 waves = K quarters (128 h). Wave's Wl column block (128 h x 16 d fp32 =
// 8 KB) staged via width-4 gathers: instr (ks,j) -> lane l fetches the float at
// row wv*128+ks*32+(l>>4)*8+j, col d0+(l&15) (4 rows x 64 B fully coalesced).
// Pack reads stride-256B -> bank = lane%32, conflict-free. 44 KB LDS -> 3 blk/CU.
__global__ __launch_bounds__(256, 2) void linear_kernel(
    const short* __restrict__ act, const float* __restrict__ Wl,
    const int* __restrict__ easgn, const float* __restrict__ wts,
    float* __restrict__ out)
{
    const int e  = blockIdx.y;
    const int d0 = blockIdx.x * 16;
    const int tid = threadIdx.x;
    const int wv   = tid >> 6;
    const int lane = tid & 63;
    const int n    = lane & 15;
    const int quad = lane >> 4;

    __shared__ __align__(16) float stage[4][2048];   // 8 KB per wave
    __shared__ float red[4][2][4][64];               // 8 KB
    __shared__ int   toks[LTOK];
    __shared__ float wsl[LTOK];
    __shared__ int   lcnt;

    const int4 eg = ((const int4*)easgn)[tid];   // issued first

    // ---- async stage: 32 instrs x 256 B per wave ----
    const float* Wbase = Wl + ((size_t)e * HDIM + wv * 128 + quad * 8) * DDIM + d0 + n;
#pragma unroll
    for (int ks = 0; ks < 4; ++ks) {
#pragma unroll
        for (int j = 0; j < 8; ++j)
            stage4(Wbase + (size_t)(ks * 32 + j) * DDIM, (char*)&stage[wv][0] + (ks * 8 + j) * 256);
    }

    // ---- pack ----
    __builtin_amdgcn_s_waitcnt(0x0f70);   // vmcnt(0)
    short8 Bl[4];
#pragma unroll
    for (int ks = 0; ks < 4; ++ks) {
        float w[8];
#pragma unroll
        for (int j = 0; j < 8; ++j)
            w[j] = stage[wv][(ks * 8 + j) * 64 + lane];
        union { short8 s; unsigned u[4]; } B;
        B.u[0] = bpack(w[0], w[1]);
        B.u[1] = bpack(w[2], w[3]);
        B.u[2] = bpack(w[4], w[5]);
        B.u[3] = bpack(w[6], w[7]);
        Bl[ks] = B.s;
    }

    // ---- self-select scan ----
    if (tid == 0) lcnt = 0;
    __syncthreads();
    if (eg.x == e) { int p = atomicAdd(&lcnt, 1); toks[p] = 4 * tid;     wsl[p] = wts[4 * tid]; }
    if (eg.y == e) { int p = atomicAdd(&lcnt, 1); toks[p] = 4 * tid + 1; wsl[p] = wts[4 * tid + 1]; }
    if (eg.z == e) { int p = atomicAdd(&lcnt, 1); toks[p] = 4 * tid + 2; wsl[p] = wts[4 * tid + 2]; }
    if (eg.w == e) { int p = atomicAdd(&lcnt, 1); toks[p] = 4 * tid + 3; wsl[p] = wts[4 * tid + 3]; }
    __syncthreads();
    const int Ne = lcnt;
    if (Ne == 0) return;

    for (int mb = 0; mb < Ne; mb += 32) {
        int arow[2];
#pragma unroll
        for (int i = 0; i < 2; ++i) {
            int s = mb + i * 16 + n;
            arow[i] = toks[s < Ne ? s : Ne - 1];   // slot id = act row
        }
        floatx4 acc[2] = {};
#pragma unroll
        for (int ks = 0; ks < 4; ++ks) {
            const int ko = wv * 128 + ks * 32 + quad * 8;
#pragma unroll
            for (int i = 0; i < 2; ++i) {
                const short8 A = *(const short8*)(act + (size_t)arow[i] * HDIM + ko);
                acc[i] = __builtin_amdgcn_mfma_f32_16x16x32_bf16(A, Bl[ks], acc[i], 0, 0, 0);
            }
        }
#pragma unroll
        for (int i = 0; i < 2; ++i)
#pragma unroll
            for (int r = 0; r < 4; ++r)
                red[wv][i][r][lane] = acc[i][r];
        __syncthreads();

        {
            const int i = wv & 1;
            const int u = wv >> 1;
#pragma unroll
            for (int rr = 0; rr < 2; ++rr) {
                const int r = u * 2 + rr;
                const int s = mb + i * 16 + quad * 4 + r;
                if (s < Ne) {
                    const int slot = toks[s];
                    const float v = ((red[0][i][r][lane] + red[1][i][r][lane]) +
                                     (red[2][i][r][lane] + red[3][i][r][lane])) * wsl[s];
                    atomicAdd(&out[(size_t)(slot >> 1) * DDIM + d0 + n], v);
                }
            }
        }
        __syncthreads();
    }
}

extern "C" void kernel_launch(void* const* d_in, const int* in_sizes, int n_in,
                              void* d_out, int out_size, void* d_ws, size_t ws_size,
                              hipStream_t stream)
{
    const float* x   = (const float*)d_in[0];
    const float* rs  = (const float*)d_in[1];
    const float* Wr  = (const float*)d_in[2];
    const float* G   = (const float*)d_in[3];
    const float* Wl  = (const float*)d_in[4];
    const float* pes = (const float*)d_in[5];
    float* out = (float*)d_out;

    char* ws = (char*)d_ws;
    int*   easgn = (int*)(ws);
    float* wts   = (float*)(ws + 4096);
    short* xb    = (short*)(ws + 8192);
    short* act   = (short*)(ws + 532480);

    router_kernel<<<dim3(LTOK), dim3(64), 0, stream>>>(x, rs, Wr, pes, easgn, wts, xb, out);
    gates_kernel<<<dim3(32, NEXP), dim3(256), 0, stream>>>(xb, G, easgn, act);
    linear_kernel<<<dim3(32, NEXP), dim3(256), 0, stream>>>(act, Wl, easgn, wts, out);
}